// Round 4
// baseline (596.626 us; speedup 1.0000x reference)
//
#include <hip/hip_runtime.h>

typedef unsigned short u16;
typedef __attribute__((ext_vector_type(8))) u16 u16x8;
typedef __attribute__((ext_vector_type(8))) __bf16 bf16x8;
typedef __attribute__((ext_vector_type(4))) float floatx4;
typedef __attribute__((ext_vector_type(16))) float floatx16;
typedef __attribute__((ext_vector_type(4))) unsigned int u32x4;

#define MFMA16(a, b, c) __builtin_amdgcn_mfma_f32_16x16x32_bf16( \
    __builtin_bit_cast(bf16x8, a), __builtin_bit_cast(bf16x8, b), c, 0, 0, 0)
#define MFMA32(a, b, c) __builtin_amdgcn_mfma_f32_32x32x16_bf16( \
    __builtin_bit_cast(bf16x8, a), __builtin_bit_cast(bf16x8, b), c, 0, 0, 0)

#if __has_builtin(__builtin_amdgcn_exp2f)
#define EXP2(x) __builtin_amdgcn_exp2f(x)
#else
#define EXP2(x) exp2f(x)
#endif

__device__ __forceinline__ float bf2f(u16 h) {
  unsigned u = ((unsigned)h) << 16;
  float f;
  __builtin_memcpy(&f, &u, 4);
  return f;
}
__device__ __forceinline__ u16 f2bf(float f) {
  unsigned u;
  __builtin_memcpy(&u, &f, 4);
  u += 0x7fff + ((u >> 16) & 1);  // round-to-nearest-even
  return (u16)(u >> 16);
}

// v_cvt_pk_bf16_f32: dst = {lo: bf16(a), hi: bf16(b)} (no builtin on gfx950)
__device__ __forceinline__ unsigned cvt_pk_bf16(float a, float b) {
  unsigned r;
  asm("v_cvt_pk_bf16_f32 %0, %1, %2" : "=v"(r) : "v"(a), "v"(b));
  return r;
}
// v_permlane32_swap_b32: a.lanes[32:63] <-> b.lanes[0:31]
__device__ __forceinline__ void pl32_swap(unsigned& a, unsigned& b) {
  asm("v_permlane32_swap_b32 %0, %1" : "+v"(a), "+v"(b));
}

typedef __attribute__((address_space(1))) const unsigned int gas_u32;
typedef __attribute__((address_space(3))) unsigned int las_u32;

__device__ __forceinline__ void gld_lds16(const u16* g, u16* l) {
  __builtin_amdgcn_global_load_lds((gas_u32*)g, (las_u32*)l, 16, 0, 0);
}

// ---- weight transpose+convert: in fp32 [R,C] -> out bf16 [C,R] ----
__global__ __launch_bounds__(256) void transpose_k(const float* __restrict__ in,
                                                   u16* __restrict__ out, int R, int C) {
  __shared__ u16 tile[64][65];
  int c0 = blockIdx.x * 64, r0 = blockIdx.y * 64;
  int tc = threadIdx.x & 63, tr = threadIdx.x >> 6;
#pragma unroll
  for (int i = 0; i < 16; ++i)
    tile[tr + i * 4][tc] = f2bf(in[(size_t)(r0 + tr + i * 4) * C + c0 + tc]);
  __syncthreads();
#pragma unroll
  for (int i = 0; i < 16; ++i)
    out[(size_t)(c0 + tr + i * 4) * R + r0 + tc] = tile[tc][tr + i * 4];
}

// ---- fp32 -> bf16 bulk convert (8 elems/thread) ----
__global__ __launch_bounds__(256) void convert_k(const float* __restrict__ in,
                                                 u16* __restrict__ out) {
  size_t idx = ((size_t)blockIdx.x * 256 + threadIdx.x) * 8;
  floatx4 f0 = *(const floatx4*)(in + idx);
  floatx4 f1 = *(const floatx4*)(in + idx + 4);
  u16x8 o;
#pragma unroll
  for (int e = 0; e < 4; ++e) o[e] = f2bf(f0[e]);
#pragma unroll
  for (int e = 0; e < 4; ++e) o[4 + e] = f2bf(f1[e]);
  *(u16x8*)(out + idx) = o;
}

// ---- GEMM v3: C[M,N] = A[M,K] * BT[N,K]^T + bias, optional relu ----
// 128x128 tile, BK=32, FIVE LDS buffers = depth-4 prefetch pipeline:
// one raw s_barrier + counted s_waitcnt vmcnt(12) per K-step (never drains the
// 3 younger tiles in flight) -> HBM latency (~900cy) covered by 4 iterations.
// XOR swizzle gc = cc ^ ((row>>1)&3): linear global_load_lds dest, swizzled
// global src + swizzled ds_read (same involution both sides); 2-way bank
// aliasing on ds_read is free. Requires K >= 128 (nk >= 4).
template <bool C_F32, bool BIAS_ROW>
__global__ __launch_bounds__(256, 2) void gemm_bt(const u16* __restrict__ A,
                                                  const u16* __restrict__ BT,
                                                  const float* __restrict__ bias,
                                                  void* __restrict__ Cv, int M, int N, int K,
                                                  int relu) {
  __shared__ __align__(16) u16 As[5][128 * 32];
  __shared__ __align__(16) u16 Bs[5][128 * 32];
  const int tid = threadIdx.x, lane = tid & 63, wave = tid >> 6;
  const int quad = lane >> 4, l15 = lane & 15;
  const int wr = wave >> 1, wc = wave & 1;
  const int m0 = blockIdx.x * 128, n0 = blockIdx.y * 128;

  floatx4 acc[4][4] = {};

  // stage K-tile kt (32 cols) into buffer buf. 4 vm-ops per wave per stage.
  auto stage = [&](int kt, int buf) {
    int k0 = kt * 32;
#pragma unroll
    for (int p = 0; p < 2; ++p) {
      int chunk = p * 256 + tid;           // 0..511 ; 4 x 16B chunks per row
      int row = chunk >> 2, cc = chunk & 3;
      int gc = cc ^ ((row >> 1) & 3);
      int ldsoff = (p * 256 + wave * 64) * 8;  // wave-uniform base; lanes +16B
      gld_lds16(A + (size_t)(m0 + row) * K + k0 + gc * 8, &As[buf][ldsoff]);
      gld_lds16(BT + (size_t)(n0 + row) * K + k0 + gc * 8, &Bs[buf][ldsoff]);
    }
  };

  const int nk = K >> 5;
  stage(0, 0);
  stage(1, 1);
  stage(2, 2);
  stage(3, 3);

  int bc = 0, bn = 4;
  for (int kt = 0; kt < nk; ++kt) {
    // wait for tile kt only: 4 vm-ops per staged-ahead tile stay in flight
    const int rem = nk - 1 - kt;
    if (rem >= 3)
      asm volatile("s_waitcnt vmcnt(12)" ::: "memory");
    else if (rem == 2)
      asm volatile("s_waitcnt vmcnt(8)" ::: "memory");
    else if (rem == 1)
      asm volatile("s_waitcnt vmcnt(4)" ::: "memory");
    else
      asm volatile("s_waitcnt vmcnt(0)" ::: "memory");
    __builtin_amdgcn_sched_barrier(0);
    __builtin_amdgcn_s_barrier();  // all waves: tile kt resident; buf[bn] reads done

    if (kt + 4 < nk) stage(kt + 4, bn);  // overwrites buf[(kt-1)%5], reads finished

    u16x8 af[4], bfr[4];
#pragma unroll
    for (int i = 0; i < 4; ++i) {
      int r = wr * 64 + i * 16 + l15;
      af[i] = *(const u16x8*)(&As[bc][r * 32 + ((quad ^ ((r >> 1) & 3)) * 8)]);
    }
#pragma unroll
    for (int j = 0; j < 4; ++j) {
      int r = wc * 64 + j * 16 + l15;
      bfr[j] = *(const u16x8*)(&Bs[bc][r * 32 + ((quad ^ ((r >> 1) & 3)) * 8)]);
    }
    __builtin_amdgcn_s_setprio(1);
#pragma unroll
    for (int i = 0; i < 4; ++i)
#pragma unroll
      for (int j = 0; j < 4; ++j) acc[i][j] = MFMA16(af[i], bfr[j], acc[i][j]);
    __builtin_amdgcn_s_setprio(0);

    if (++bc == 5) bc = 0;
    if (++bn == 5) bn = 0;
  }

#pragma unroll
  for (int j = 0; j < 4; ++j) {
    int col = n0 + wc * 64 + j * 16 + l15;
    float bv = BIAS_ROW ? 0.f : bias[col];
#pragma unroll
    for (int i = 0; i < 4; ++i) {
      int row = m0 + wr * 64 + i * 16 + quad * 4;
#pragma unroll
      for (int r = 0; r < 4; ++r) {
        float v = acc[i][j][r] + (BIAS_ROW ? bias[row + r] : bv);
        if (relu) v = fmaxf(v, 0.f);
        if (C_F32)
          ((float*)Cv)[(size_t)(row + r) * N + col] = v;
        else
          ((u16*)Cv)[(size_t)(row + r) * N + col] = f2bf(v);
      }
    }
  }
}

// ---------------- flash attention v5: 32x32 swapped-operand, in-register P ----------------
// grid (S/128, H, B), 256 threads (4 waves), each wave owns 32 q-rows.
// Sᵀ = mfma32(K-frag, Q-frag): lane holds Sᵀ[t][q=l&31], t = (r&3)+8*(r>>2)+4*(l>>5).
// Fixed-base softmax (p = 2^s, log2e folded into Q pre-scale) is fully lane-local.
// P -> PV B-frag via v_cvt_pk_bf16_f32 + v_permlane32_swap (T12) — no LDS round trip.
// Oᵀ = mfma32(Vᵀ-frag, P-frag); epilogue: LDS transpose -> coalesced stores.
// K/V tiles XOR-swizzled in LDS (16B chunks): conflict-free ds_read_b128 + linear
// global_load_lds staging. One barrier per KV iter.
__global__ __launch_bounds__(256, 4) void attn_k(const u16* __restrict__ Q,
                                                 const u16* __restrict__ Km,
                                                 const u16* __restrict__ Vt,
                                                 u16* __restrict__ O) {
  __shared__ __align__(16) u16 sh[16384];  // 32 KB: Ks[2]=sh+{0,4096}, Vs[2]=sh+8192+{0,4096}
  const int tid = threadIdx.x, lane = tid & 63, w = tid >> 6;
  const int hi = lane >> 5, l31 = lane & 31;
  const int b = blockIdx.z, h = blockIdx.y, q0 = blockIdx.x * 128;
  const size_t tokbase = (size_t)b * 2048;

  // ---- stage Q tile 128x64 into sh (swizzled), extract frags, pre-scale ----
#pragma unroll
  for (int p = 0; p < 4; ++p) {
    int chunk = p * 256 + tid, row = chunk >> 3, cc = chunk & 7;
    int gc = cc ^ (row & 7);
    gld_lds16(Q + (tokbase + q0 + row) * 1024 + h * 64 + gc * 8, sh + (p * 256 + w * 64) * 8);
  }
  __syncthreads();
  u16x8 qf[4];  // lane: Q[q=l31][d = kt*16 + hi*8 + e], scaled by 0.125*log2(e)
#pragma unroll
  for (int kt = 0; kt < 4; ++kt) {
    int r = w * 32 + l31;
    int sel = (kt * 2 + hi) ^ (r & 7);
    u16x8 t = *(const u16x8*)(sh + r * 64 + sel * 8);
#pragma unroll
    for (int e = 0; e < 8; ++e) t[e] = f2bf(bf2f(t[e]) * 0.18033688011f);
    qf[kt] = t;
  }
  __syncthreads();  // all Q reads in regs before K staging overwrites sh

  floatx16 oacc0 = {}, oacc1 = {};
  float lsum = 0.f;

  auto stage = [&](int it2, int buf) {
    int t0 = it2 * 64;
#pragma unroll
    for (int p = 0; p < 2; ++p) {
      int chunk = p * 256 + tid;
      int row = chunk >> 3, cc = chunk & 7;
      int gc = cc ^ (row & 7);
      int ldsoff = (p * 256 + w * 64) * 8;  // wave-uniform base; lanes +16B
      gld_lds16(Km + (tokbase + t0 + row) * 1024 + h * 64 + gc * 8, sh + buf * 4096 + ldsoff);
      gld_lds16(Vt + ((size_t)(h * 64 + row)) * 8192 + tokbase + t0 + gc * 8,
                sh + 8192 + buf * 4096 + ldsoff);
    }
  };

  stage(0, 0);

  for (int it = 0; it < 32; ++it) {
    const int cur = it & 1;
    __syncthreads();  // buf[cur] staged (barrier drains vmcnt); buf[cur^1] reads done
    if (it + 1 < 32) stage(it + 1, cur ^ 1);
    const u16* kb = sh + cur * 4096;
    const u16* vb = sh + 8192 + cur * 4096;

    u32x4 pf[4];  // PV B-frags, one per 16-t k-tile
#pragma unroll
    for (int tt = 0; tt < 2; ++tt) {
      // Sᵀ tile: rows t = tt*32.., cols q
      u16x8 ka[4];
#pragma unroll
      for (int kt = 0; kt < 4; ++kt) {
        int r = tt * 32 + l31;
        ka[kt] = *(const u16x8*)(kb + r * 64 + (((kt * 2 + hi) ^ (r & 7)) * 8));
      }
      floatx16 s = {};
      __builtin_amdgcn_s_setprio(1);
#pragma unroll
      for (int kt = 0; kt < 4; ++kt) s = MFMA32(ka[kt], qf[kt], s);
      __builtin_amdgcn_s_setprio(0);

      float p[16];
#pragma unroll
      for (int r = 0; r < 16; ++r) p[r] = EXP2(s[r]);
#pragma unroll
      for (int r = 0; r < 16; ++r) lsum += p[r];
      // pack + lane-swap into B-frag layout: k-tile t = tt*32 + half*16
#pragma unroll
      for (int half = 0; half < 2; ++half) {
        unsigned X0 = cvt_pk_bf16(p[half * 8 + 0], p[half * 8 + 1]);
        unsigned X1 = cvt_pk_bf16(p[half * 8 + 2], p[half * 8 + 3]);
        unsigned Y0 = cvt_pk_bf16(p[half * 8 + 4], p[half * 8 + 5]);
        unsigned Y1 = cvt_pk_bf16(p[half * 8 + 6], p[half * 8 + 7]);
        pl32_swap(X0, Y0);
        pl32_swap(X1, Y1);
        u32x4 f;
        f[0] = X0; f[1] = X1; f[2] = Y0; f[3] = Y1;
        pf[tt * 2 + half] = f;
      }
    }

    // Oᵀ += Vᵀ Pᵀ
    {
      u16x8 va[4];
#pragma unroll
      for (int kt = 0; kt < 4; ++kt) {
        int r = l31;  // d-tile 0
        va[kt] = *(const u16x8*)(vb + r * 64 + (((kt * 2 + hi) ^ (r & 7)) * 8));
      }
      __builtin_amdgcn_s_setprio(1);
#pragma unroll
      for (int kt = 0; kt < 4; ++kt)
        oacc0 = MFMA32(va[kt], __builtin_bit_cast(u16x8, pf[kt]), oacc0);
      __builtin_amdgcn_s_setprio(0);
#pragma unroll
      for (int kt = 0; kt < 4; ++kt) {
        int r = 32 + l31;  // d-tile 1
        va[kt] = *(const u16x8*)(vb + r * 64 + (((kt * 2 + hi) ^ (r & 7)) * 8));
      }
      __builtin_amdgcn_s_setprio(1);
#pragma unroll
      for (int kt = 0; kt < 4; ++kt)
        oacc1 = MFMA32(va[kt], __builtin_bit_cast(u16x8, pf[kt]), oacc1);
      __builtin_amdgcn_s_setprio(0);
    }
  }

  // ---- epilogue: normalize, LDS transpose, coalesced store ----
  __syncthreads();  // compute done; sh reusable as [128][72] u16
  float tot = lsum + __shfl_xor(lsum, 32);  // lane pair (l, l+32) holds same q
  float inv = 1.0f / fmaxf(tot, 1e-30f);
  const int qrow = w * 32 + l31;
#pragma unroll
  for (int dt = 0; dt < 2; ++dt) {
    const floatx16& oa = dt ? oacc1 : oacc0;
#pragma unroll
    for (int pr = 0; pr < 8; ++pr) {
      float a = oa[2 * pr] * inv, bb = oa[2 * pr + 1] * inv;
      unsigned pkw = (unsigned)f2bf(a) | ((unsigned)f2bf(bb) << 16);
      int d = dt * 32 + (pr & 1) * 2 + (pr >> 1) * 8 + 4 * hi;
      *(unsigned*)(sh + qrow * 72 + d) = pkw;
    }
  }
  __syncthreads();
#pragma unroll
  for (int p2 = 0; p2 < 4; ++p2) {
    int c = p2 * 64 + lane, rl = c >> 3, cc = c & 7;
    u16x8 vv = *(const u16x8*)(sh + (w * 32 + rl) * 72 + cc * 8);
    *(u16x8*)(O + (tokbase + q0 + w * 32 + rl) * 1024 + h * 64 + cc * 8) = vv;
  }
}

// ---- fused residual + layernorm: out = LN(A + B) * g + be ----
template <bool A_F32, bool B_F32, bool OUT_F32>
__global__ __launch_bounds__(256) void ln_k(const void* __restrict__ Av,
                                            const void* __restrict__ Bv,
                                            const float* __restrict__ g,
                                            const float* __restrict__ be,
                                            void* __restrict__ outv) {
  const int lane = threadIdx.x & 63, wave = threadIdx.x >> 6;
  const size_t row = (size_t)blockIdx.x * 4 + wave;
  const size_t base = row * 1024 + lane * 16;
  float v[16];
  if (A_F32) {
    const float* a = (const float*)Av + base;
#pragma unroll
    for (int q = 0; q < 4; ++q) {
      floatx4 t = *(const floatx4*)(a + q * 4);
#pragma unroll
      for (int e = 0; e < 4; ++e) v[q * 4 + e] = t[e];
    }
  } else {
    const u16* a = (const u16*)Av + base;
    u16x8 a0 = *(const u16x8*)a, a1 = *(const u16x8*)(a + 8);
#pragma unroll
    for (int e = 0; e < 8; ++e) {
      v[e] = bf2f(a0[e]);
      v[e + 8] = bf2f(a1[e]);
    }
  }
  if (B_F32) {
    const float* bb = (const float*)Bv + base;
#pragma unroll
    for (int q = 0; q < 4; ++q) {
      floatx4 t = *(const floatx4*)(bb + q * 4);
#pragma unroll
      for (int e = 0; e < 4; ++e) v[q * 4 + e] += t[e];
    }
  } else {
    const u16* bb = (const u16*)Bv + base;
    u16x8 b0 = *(const u16x8*)bb, b1 = *(const u16x8*)(bb + 8);
#pragma unroll
    for (int e = 0; e < 8; ++e) {
      v[e] += bf2f(b0[e]);
      v[e + 8] += bf2f(b1[e]);
    }
  }
  float sum = 0.f, sq = 0.f;
#pragma unroll
  for (int e = 0; e < 16; ++e) {
    sum += v[e];
    sq += v[e] * v[e];
  }
#pragma unroll
  for (int mk = 1; mk < 64; mk <<= 1) {
    sum += __shfl_xor(sum, mk);
    sq += __shfl_xor(sq, mk);
  }
  float mu = sum * (1.f / 1024.f);
  float var = fmaxf(sq * (1.f / 1024.f) - mu * mu, 0.f);
  float rstd = rsqrtf(var + 1e-5f);
  if (OUT_F32) {
    float* o = (float*)outv + base;
#pragma unroll
    for (int q = 0; q < 4; ++q) {
      floatx4 t;
#pragma unroll
      for (int e = 0; e < 4; ++e) {
        int c = lane * 16 + q * 4 + e;
        t[e] = (v[q * 4 + e] - mu) * rstd * g[c] + be[c];
      }
      *(floatx4*)(o + q * 4) = t;
    }
  } else {
    u16x8 o0, o1;
#pragma unroll
    for (int e = 0; e < 8; ++e) {
      int c = lane * 16 + e;
      o0[e] = f2bf((v[e] - mu) * rstd * g[c] + be[c]);
      o1[e] = f2bf((v[e + 8] - mu) * rstd * g[c + 8] + be[c + 8]);
    }
    *(u16x8*)((u16*)outv + base) = o0;
    *(u16x8*)((u16*)outv + base + 8) = o1;
  }
}

extern "C" void kernel_launch(void* const* d_in, const int* in_sizes, int n_in, void* d_out,
                              int out_size, void* d_ws, size_t ws_size, hipStream_t stream) {
  const float* x = (const float*)d_in[0];
  const float* wq = (const float*)d_in[1];
  const float* bq = (const float*)d_in[2];
  const float* wk = (const float*)d_in[3];
  const float* bk = (const float*)d_in[4];
  const float* wv = (const float*)d_in[5];
  const float* bv = (const float*)d_in[6];
  const float* wo = (const float*)d_in[7];
  const float* bo = (const float*)d_in[8];
  const float* w1 = (const float*)d_in[9];
  const float* b1 = (const float*)d_in[10];
  const float* w2 = (const float*)d_in[11];
  const float* b2 = (const float*)d_in[12];
  const float* g1 = (const float*)d_in[13];
  const float* be1 = (const float*)d_in[14];
  const float* g2 = (const float*)d_in[15];
  const float* be2 = (const float*)d_in[16];
  float* out = (float*)d_out;

  // ws: bf16 weights (24 MB) + 6 x 16 MB bf16 slots = 120 MB
  u16* W = (u16*)d_ws;
  const size_t M1 = (size_t)1 << 20;
  u16* wqT = W;
  u16* wkT = wqT + M1;
  u16* wvT = wkT + M1;
  u16* woT = wvT + M1;
  u16* w1T = woT + M1;       // [4096,1024]
  u16* w2T = w1T + 4 * M1;   // [1024,4096]
  u16* arena = w2T + 4 * M1;
  const size_t S8M = (size_t)8 << 20;
  u16* xb = arena;            // slot 0: x bf16; later X1
  u16* Qb = arena + S8M;      // slot 1: Q; later attn_out; later F1 part
  u16* Kb = arena + 2 * S8M;  // slot 2
  u16* Vtb = arena + 3 * S8M; // slot 3: V^T [1024][8192] (row=h*64+d, col=b*2048+t)
  u16* Cb = arena + 4 * S8M;  // slot 4 (ctx)
  u16* AO = Qb;               // attn_out (Q dead after attn)
  u16* X1 = xb;               // ln1 out (xb dead after QKV gemms)
  u16* F1 = Qb;               // ffn1 hidden = slots 1-4 (64 MB)

  dim3 blk(256);
  transpose_k<<<dim3(16, 16), blk, 0, stream>>>(wq, wqT, 1024, 1024);
  transpose_k<<<dim3(16, 16), blk, 0, stream>>>(wk, wkT, 1024, 1024);
  transpose_k<<<dim3(16, 16), blk, 0, stream>>>(wv, wvT, 1024, 1024);
  transpose_k<<<dim3(16, 16), blk, 0, stream>>>(wo, woT, 1024, 1024);
  transpose_k<<<dim3(64, 16), blk, 0, stream>>>(w1, w1T, 1024, 4096);
  transpose_k<<<dim3(16, 64), blk, 0, stream>>>(w2, w2T, 4096, 1024);
  convert_k<<<4096, blk, 0, stream>>>(x, xb);

  // Q,K projections; V computed transposed: Vt[d][t] = sum_k wvT[d][k]*x[t][k] + bv[d]
  gemm_bt<false, false><<<dim3(64, 8), blk, 0, stream>>>(xb, wqT, bq, Qb, 8192, 1024, 1024, 0);
  gemm_bt<false, false><<<dim3(64, 8), blk, 0, stream>>>(xb, wkT, bk, Kb, 8192, 1024, 1024, 0);
  gemm_bt<false, true><<<dim3(8, 64), blk, 0, stream>>>(wvT, xb, bv, Vtb, 1024, 8192, 1024, 0);

  // attention (V already transposed)
  attn_k<<<dim3(16, 16, 4), blk, 0, stream>>>(Qb, Kb, Vtb, Cb);

  // output projection + LN1
  gemm_bt<false, false><<<dim3(64, 8), blk, 0, stream>>>(Cb, woT, bo, AO, 8192, 1024, 1024, 0);
  ln_k<true, false, false><<<2048, blk, 0, stream>>>(x, AO, g1, be1, X1);

  // FFN
  gemm_bt<false, false><<<dim3(64, 32), blk, 0, stream>>>(X1, w1T, b1, F1, 8192, 4096, 1024, 1);
  gemm_bt<true, false><<<dim3(64, 8), blk, 0, stream>>>(F1, w2T, b2, out, 8192, 1024, 4096, 0);
  ln_k<false, true, true><<<2048, blk, 0, stream>>>(X1, out, g2, be2, out);
}

// Round 5
// 486.589 us; speedup vs baseline: 1.2261x; 1.2261x over previous
//
#include <hip/hip_runtime.h>

typedef unsigned short u16;
typedef __attribute__((ext_vector_type(8))) u16 u16x8;
typedef __attribute__((ext_vector_type(8))) __bf16 bf16x8;
typedef __attribute__((ext_vector_type(4))) float floatx4;
typedef __attribute__((ext_vector_type(16))) float floatx16;
typedef __attribute__((ext_vector_type(4))) unsigned int u32x4;

#define MFMA16(a, b, c) __builtin_amdgcn_mfma_f32_16x16x32_bf16( \
    __builtin_bit_cast(bf16x8, a), __builtin_bit_cast(bf16x8, b), c, 0, 0, 0)
#define MFMA32(a, b, c) __builtin_amdgcn_mfma_f32_32x32x16_bf16( \
    __builtin_bit_cast(bf16x8, a), __builtin_bit_cast(bf16x8, b), c, 0, 0, 0)

#if __has_builtin(__builtin_amdgcn_exp2f)
#define EXP2(x) __builtin_amdgcn_exp2f(x)
#else
#define EXP2(x) exp2f(x)
#endif

__device__ __forceinline__ float bf2f(u16 h) {
  unsigned u = ((unsigned)h) << 16;
  float f;
  __builtin_memcpy(&f, &u, 4);
  return f;
}
__device__ __forceinline__ u16 f2bf(float f) {
  unsigned u;
  __builtin_memcpy(&u, &f, 4);
  u += 0x7fff + ((u >> 16) & 1);  // round-to-nearest-even
  return (u16)(u >> 16);
}

// v_cvt_pk_bf16_f32: dst = {lo: bf16(a), hi: bf16(b)} (no builtin on gfx950)
__device__ __forceinline__ unsigned cvt_pk_bf16(float a, float b) {
  unsigned r;
  asm("v_cvt_pk_bf16_f32 %0, %1, %2" : "=v"(r) : "v"(a), "v"(b));
  return r;
}
// v_permlane32_swap_b32: a.lanes[32:63] <-> b.lanes[0:31]
__device__ __forceinline__ void pl32_swap(unsigned& a, unsigned& b) {
  asm("v_permlane32_swap_b32 %0, %1" : "+v"(a), "+v"(b));
}

typedef __attribute__((address_space(1))) const unsigned int gas_u32;
typedef __attribute__((address_space(3))) unsigned int las_u32;

__device__ __forceinline__ void gld_lds16(const u16* g, u16* l) {
  __builtin_amdgcn_global_load_lds((gas_u32*)g, (las_u32*)l, 16, 0, 0);
}

// ---- weight transpose+convert: in fp32 [R,C] -> out bf16 [C,R] ----
__global__ __launch_bounds__(256) void transpose_k(const float* __restrict__ in,
                                                   u16* __restrict__ out, int R, int C) {
  __shared__ u16 tile[64][65];
  int c0 = blockIdx.x * 64, r0 = blockIdx.y * 64;
  int tc = threadIdx.x & 63, tr = threadIdx.x >> 6;
#pragma unroll
  for (int i = 0; i < 16; ++i)
    tile[tr + i * 4][tc] = f2bf(in[(size_t)(r0 + tr + i * 4) * C + c0 + tc]);
  __syncthreads();
#pragma unroll
  for (int i = 0; i < 16; ++i)
    out[(size_t)(c0 + tr + i * 4) * R + r0 + tc] = tile[tc][tr + i * 4];
}

// ---- batched 1024x1024 transpose for the 4 square weights (1 launch) ----
__global__ __launch_bounds__(256) void transpose4_k(const float* __restrict__ i0,
                                                    const float* __restrict__ i1,
                                                    const float* __restrict__ i2,
                                                    const float* __restrict__ i3,
                                                    u16* __restrict__ o0, u16* __restrict__ o1,
                                                    u16* __restrict__ o2, u16* __restrict__ o3) {
  __shared__ u16 tile[64][65];
  const float* in;
  u16* out;
  switch (blockIdx.z) {
    case 0: in = i0; out = o0; break;
    case 1: in = i1; out = o1; break;
    case 2: in = i2; out = o2; break;
    default: in = i3; out = o3; break;
  }
  int c0 = blockIdx.x * 64, r0 = blockIdx.y * 64;
  int tc = threadIdx.x & 63, tr = threadIdx.x >> 6;
#pragma unroll
  for (int i = 0; i < 16; ++i)
    tile[tr + i * 4][tc] = f2bf(in[(size_t)(r0 + tr + i * 4) * 1024 + c0 + tc]);
  __syncthreads();
#pragma unroll
  for (int i = 0; i < 16; ++i)
    out[(size_t)(c0 + tr + i * 4) * 1024 + r0 + tc] = tile[tc][tr + i * 4];
}

// ---- fp32 -> bf16 bulk convert (8 elems/thread) ----
__global__ __launch_bounds__(256) void convert_k(const float* __restrict__ in,
                                                 u16* __restrict__ out) {
  size_t idx = ((size_t)blockIdx.x * 256 + threadIdx.x) * 8;
  floatx4 f0 = *(const floatx4*)(in + idx);
  floatx4 f1 = *(const floatx4*)(in + idx + 4);
  u16x8 o;
#pragma unroll
  for (int e = 0; e < 4; ++e) o[e] = f2bf(f0[e]);
#pragma unroll
  for (int e = 0; e < 4; ++e) o[4 + e] = f2bf(f1[e]);
  *(u16x8*)(out + idx) = o;
}

// ---- GEMM (R3-proven): C[M,N] = A[M,K] * BT[N,K]^T + bias, optional relu ----
// 128x128 tile, BK=64, double-buffered LDS with prefetch-overlap (stage k+1
// issued right after the single per-iter barrier -> load latency hides under
// MFMA), XOR-swizzled rows (128B) for conflict-free ds_read_b128 while keeping
// the global_load_lds destination linear (swizzle applied to global src chunk).
// bias split: col < bsplit ? bias[col] : bias2[col-bsplit] (for fused QK).
template <bool C_F32, bool BIAS_ROW>
__global__ __launch_bounds__(256, 2) void gemm_bt(const u16* __restrict__ A,
                                                  const u16* __restrict__ BT,
                                                  const float* __restrict__ bias,
                                                  const float* __restrict__ bias2, int bsplit,
                                                  void* __restrict__ Cv, int M, int N, int K,
                                                  int relu) {
  __shared__ __align__(16) u16 As[2][128 * 64];
  __shared__ __align__(16) u16 Bs[2][128 * 64];
  const int tid = threadIdx.x, lane = tid & 63, wave = tid >> 6;
  const int quad = lane >> 4, l15 = lane & 15;
  const int wr = wave >> 1, wc = wave & 1;
  const int m0 = blockIdx.x * 128, n0 = blockIdx.y * 128;

  floatx4 acc[4][4] = {};

  // stage K-tile kt into buffer buf: LDS slot (row, cc) <- global chunk (row, cc^(row&7))
  auto stage = [&](int kt, int buf) {
    int k0 = kt * 64;
#pragma unroll
    for (int p = 0; p < 4; ++p) {
      int chunk = p * 256 + tid;
      int row = chunk >> 3, cc = chunk & 7;
      int gc = cc ^ (row & 7);
      int ldsoff = (p * 256 + wave * 64) * 8;  // wave-uniform base; lanes +16B
      gld_lds16(A + (size_t)(m0 + row) * K + k0 + gc * 8, &As[buf][ldsoff]);
      gld_lds16(BT + (size_t)(n0 + row) * K + k0 + gc * 8, &Bs[buf][ldsoff]);
    }
  };

  const int nk = K >> 6;
  stage(0, 0);

  for (int kt = 0; kt < nk; ++kt) {
    const int cur = kt & 1;
    __syncthreads();  // drains vmcnt: buf[cur] staged; buf[cur^1] reads (prev iter) done
    if (kt + 1 < nk) stage(kt + 1, cur ^ 1);  // in flight during this iter's compute

#pragma unroll
    for (int ks = 0; ks < 2; ++ks) {
      u16x8 af[4], bfr[4];
#pragma unroll
      for (int i = 0; i < 4; ++i) {
        int r = wr * 64 + i * 16 + l15;
        af[i] = *(const u16x8*)(&As[cur][r * 64 + (((ks * 4 + quad) ^ (r & 7)) * 8)]);
      }
#pragma unroll
      for (int j = 0; j < 4; ++j) {
        int r = wc * 64 + j * 16 + l15;
        bfr[j] = *(const u16x8*)(&Bs[cur][r * 64 + (((ks * 4 + quad) ^ (r & 7)) * 8)]);
      }
#pragma unroll
      for (int i = 0; i < 4; ++i)
#pragma unroll
        for (int j = 0; j < 4; ++j) acc[i][j] = MFMA16(af[i], bfr[j], acc[i][j]);
    }
  }

#pragma unroll
  for (int j = 0; j < 4; ++j) {
    int col = n0 + wc * 64 + j * 16 + l15;
    float bv = 0.f;
    if (!BIAS_ROW) bv = col < bsplit ? bias[col] : bias2[col - bsplit];
#pragma unroll
    for (int i = 0; i < 4; ++i) {
      int row = m0 + wr * 64 + i * 16 + quad * 4;
#pragma unroll
      for (int r = 0; r < 4; ++r) {
        float v = acc[i][j][r] + (BIAS_ROW ? bias[row + r] : bv);
        if (relu) v = fmaxf(v, 0.f);
        if (C_F32)
          ((float*)Cv)[(size_t)(row + r) * N + col] = v;
        else
          ((u16*)Cv)[(size_t)(row + r) * N + col] = f2bf(v);
      }
    }
  }
}

// ---------------- flash attention v5: 32x32 swapped-operand, in-register P ----------------
// grid (S/128, H, B), 256 threads (4 waves), each wave owns 32 q-rows.
// Q/K read from the fused QK buffer [B*S, 2048] (Q cols h*64.., K base pre-offset
// by +1024): row stride 2048. Vt: [1024][8192]. O: [B*S,1024].
// Sᵀ = mfma32(K-frag, Q-frag); fixed-base softmax p = 2^s (log2e in Q pre-scale);
// P -> PV B-frag via v_cvt_pk_bf16_f32 + v_permlane32_swap (no LDS round trip).
// K/V tiles XOR-swizzled in LDS; one barrier per KV iter.
__global__ __launch_bounds__(256, 4) void attn_k(const u16* __restrict__ Q,
                                                 const u16* __restrict__ Km,
                                                 const u16* __restrict__ Vt,
                                                 u16* __restrict__ O) {
  __shared__ __align__(16) u16 sh[16384];  // 32 KB: Ks[2]=sh+{0,4096}, Vs[2]=sh+8192+{0,4096}
  const int tid = threadIdx.x, lane = tid & 63, w = tid >> 6;
  const int hi = lane >> 5, l31 = lane & 31;
  const int b = blockIdx.z, h = blockIdx.y, q0 = blockIdx.x * 128;
  const size_t tokbase = (size_t)b * 2048;

  // ---- stage Q tile 128x64 into sh (swizzled), extract frags, pre-scale ----
#pragma unroll
  for (int p = 0; p < 4; ++p) {
    int chunk = p * 256 + tid, row = chunk >> 3, cc = chunk & 7;
    int gc = cc ^ (row & 7);
    gld_lds16(Q + (tokbase + q0 + row) * 2048 + h * 64 + gc * 8, sh + (p * 256 + w * 64) * 8);
  }
  __syncthreads();
  u16x8 qf[4];  // lane: Q[q=l31][d = kt*16 + hi*8 + e], scaled by 0.125*log2(e)
#pragma unroll
  for (int kt = 0; kt < 4; ++kt) {
    int r = w * 32 + l31;
    int sel = (kt * 2 + hi) ^ (r & 7);
    u16x8 t = *(const u16x8*)(sh + r * 64 + sel * 8);
#pragma unroll
    for (int e = 0; e < 8; ++e) t[e] = f2bf(bf2f(t[e]) * 0.18033688011f);
    qf[kt] = t;
  }
  __syncthreads();  // all Q reads in regs before K staging overwrites sh

  floatx16 oacc0 = {}, oacc1 = {};
  float lsum = 0.f;

  auto stage = [&](int it2, int buf) {
    int t0 = it2 * 64;
#pragma unroll
    for (int p = 0; p < 2; ++p) {
      int chunk = p * 256 + tid;
      int row = chunk >> 3, cc = chunk & 7;
      int gc = cc ^ (row & 7);
      int ldsoff = (p * 256 + w * 64) * 8;  // wave-uniform base; lanes +16B
      gld_lds16(Km + (tokbase + t0 + row) * 2048 + h * 64 + gc * 8, sh + buf * 4096 + ldsoff);
      gld_lds16(Vt + ((size_t)(h * 64 + row)) * 8192 + tokbase + t0 + gc * 8,
                sh + 8192 + buf * 4096 + ldsoff);
    }
  };

  stage(0, 0);

  for (int it = 0; it < 32; ++it) {
    const int cur = it & 1;
    __syncthreads();  // buf[cur] staged (barrier drains vmcnt); buf[cur^1] reads done
    if (it + 1 < 32) stage(it + 1, cur ^ 1);
    const u16* kb = sh + cur * 4096;
    const u16* vb = sh + 8192 + cur * 4096;

    u32x4 pf[4];  // PV B-frags, one per 16-t k-tile
#pragma unroll
    for (int tt = 0; tt < 2; ++tt) {
      // Sᵀ tile: rows t = tt*32.., cols q
      u16x8 ka[4];
#pragma unroll
      for (int kt = 0; kt < 4; ++kt) {
        int r = tt * 32 + l31;
        ka[kt] = *(const u16x8*)(kb + r * 64 + (((kt * 2 + hi) ^ (r & 7)) * 8));
      }
      floatx16 s = {};
      __builtin_amdgcn_s_setprio(1);
#pragma unroll
      for (int kt = 0; kt < 4; ++kt) s = MFMA32(ka[kt], qf[kt], s);
      __builtin_amdgcn_s_setprio(0);

      float p[16];
#pragma unroll
      for (int r = 0; r < 16; ++r) p[r] = EXP2(s[r]);
#pragma unroll
      for (int r = 0; r < 16; ++r) lsum += p[r];
      // pack + lane-swap into B-frag layout: k-tile t = tt*32 + half*16
#pragma unroll
      for (int half = 0; half < 2; ++half) {
        unsigned X0 = cvt_pk_bf16(p[half * 8 + 0], p[half * 8 + 1]);
        unsigned X1 = cvt_pk_bf16(p[half * 8 + 2], p[half * 8 + 3]);
        unsigned Y0 = cvt_pk_bf16(p[half * 8 + 4], p[half * 8 + 5]);
        unsigned Y1 = cvt_pk_bf16(p[half * 8 + 6], p[half * 8 + 7]);
        pl32_swap(X0, Y0);
        pl32_swap(X1, Y1);
        u32x4 f;
        f[0] = X0; f[1] = X1; f[2] = Y0; f[3] = Y1;
        pf[tt * 2 + half] = f;
      }
    }

    // Oᵀ += Vᵀ Pᵀ
    {
      u16x8 va[4];
#pragma unroll
      for (int kt = 0; kt < 4; ++kt) {
        int r = l31;  // d-tile 0
        va[kt] = *(const u16x8*)(vb + r * 64 + (((kt * 2 + hi) ^ (r & 7)) * 8));
      }
      __builtin_amdgcn_s_setprio(1);
#pragma unroll
      for (int kt = 0; kt < 4; ++kt)
        oacc0 = MFMA32(va[kt], __builtin_bit_cast(u16x8, pf[kt]), oacc0);
      __builtin_amdgcn_s_setprio(0);
#pragma unroll
      for (int kt = 0; kt < 4; ++kt) {
        int r = 32 + l31;  // d-tile 1
        va[kt] = *(const u16x8*)(vb + r * 64 + (((kt * 2 + hi) ^ (r & 7)) * 8));
      }
      __builtin_amdgcn_s_setprio(1);
#pragma unroll
      for (int kt = 0; kt < 4; ++kt)
        oacc1 = MFMA32(va[kt], __builtin_bit_cast(u16x8, pf[kt]), oacc1);
      __builtin_amdgcn_s_setprio(0);
    }
  }

  // ---- epilogue: normalize, LDS transpose, coalesced store ----
  __syncthreads();  // compute done; sh reusable as [128][72] u16
  float tot = lsum + __shfl_xor(lsum, 32);  // lane pair (l, l+32) holds same q
  float inv = 1.0f / fmaxf(tot, 1e-30f);
  const int qrow = w * 32 + l31;
#pragma unroll
  for (int dt = 0; dt < 2; ++dt) {
    const floatx16& oa = dt ? oacc1 : oacc0;
#pragma unroll
    for (int pr = 0; pr < 8; ++pr) {
      float a = oa[2 * pr] * inv, bb = oa[2 * pr + 1] * inv;
      unsigned pkw = (unsigned)f2bf(a) | ((unsigned)f2bf(bb) << 16);
      int d = dt * 32 + (pr & 1) * 2 + (pr >> 1) * 8 + 4 * hi;
      *(unsigned*)(sh + qrow * 72 + d) = pkw;
    }
  }
  __syncthreads();
#pragma unroll
  for (int p2 = 0; p2 < 4; ++p2) {
    int c = p2 * 64 + lane, rl = c >> 3, cc = c & 7;
    u16x8 vv = *(const u16x8*)(sh + (w * 32 + rl) * 72 + cc * 8);
    *(u16x8*)(O + (tokbase + q0 + w * 32 + rl) * 1024 + h * 64 + cc * 8) = vv;
  }
}

// ---- fused residual + layernorm: out = LN(A + B) * g + be ----
template <bool A_F32, bool B_F32, bool OUT_F32>
__global__ __launch_bounds__(256) void ln_k(const void* __restrict__ Av,
                                            const void* __restrict__ Bv,
                                            const float* __restrict__ g,
                                            const float* __restrict__ be,
                                            void* __restrict__ outv) {
  const int lane = threadIdx.x & 63, wave = threadIdx.x >> 6;
  const size_t row = (size_t)blockIdx.x * 4 + wave;
  const size_t base = row * 1024 + lane * 16;
  float v[16];
  if (A_F32) {
    const float* a = (const float*)Av + base;
#pragma unroll
    for (int q = 0; q < 4; ++q) {
      floatx4 t = *(const floatx4*)(a + q * 4);
#pragma unroll
      for (int e = 0; e < 4; ++e) v[q * 4 + e] = t[e];
    }
  } else {
    const u16* a = (const u16*)Av + base;
    u16x8 a0 = *(const u16x8*)a, a1 = *(const u16x8*)(a + 8);
#pragma unroll
    for (int e = 0; e < 8; ++e) {
      v[e] = bf2f(a0[e]);
      v[e + 8] = bf2f(a1[e]);
    }
  }
  if (B_F32) {
    const float* bb = (const float*)Bv + base;
#pragma unroll
    for (int q = 0; q < 4; ++q) {
      floatx4 t = *(const floatx4*)(bb + q * 4);
#pragma unroll
      for (int e = 0; e < 4; ++e) v[q * 4 + e] += t[e];
    }
  } else {
    const u16* bb = (const u16*)Bv + base;
    u16x8 b0 = *(const u16x8*)bb, b1 = *(const u16x8*)(bb + 8);
#pragma unroll
    for (int e = 0; e < 8; ++e) {
      v[e] += bf2f(b0[e]);
      v[e + 8] += bf2f(b1[e]);
    }
  }
  float sum = 0.f, sq = 0.f;
#pragma unroll
  for (int e = 0; e < 16; ++e) {
    sum += v[e];
    sq += v[e] * v[e];
  }
#pragma unroll
  for (int mk = 1; mk < 64; mk <<= 1) {
    sum += __shfl_xor(sum, mk);
    sq += __shfl_xor(sq, mk);
  }
  float mu = sum * (1.f / 1024.f);
  float var = fmaxf(sq * (1.f / 1024.f) - mu * mu, 0.f);
  float rstd = rsqrtf(var + 1e-5f);
  if (OUT_F32) {
    float* o = (float*)outv + base;
#pragma unroll
    for (int q = 0; q < 4; ++q) {
      floatx4 t;
#pragma unroll
      for (int e = 0; e < 4; ++e) {
        int c = lane * 16 + q * 4 + e;
        t[e] = (v[q * 4 + e] - mu) * rstd * g[c] + be[c];
      }
      *(floatx4*)(o + q * 4) = t;
    }
  } else {
    u16x8 o0, o1;
#pragma unroll
    for (int e = 0; e < 8; ++e) {
      int c = lane * 16 + e;
      o0[e] = f2bf((v[e] - mu) * rstd * g[c] + be[c]);
      o1[e] = f2bf((v[e + 8] - mu) * rstd * g[c + 8] + be[c + 8]);
    }
    *(u16x8*)((u16*)outv + base) = o0;
    *(u16x8*)((u16*)outv + base + 8) = o1;
  }
}

extern "C" void kernel_launch(void* const* d_in, const int* in_sizes, int n_in, void* d_out,
                              int out_size, void* d_ws, size_t ws_size, hipStream_t stream) {
  const float* x = (const float*)d_in[0];
  const float* wq = (const float*)d_in[1];
  const float* bq = (const float*)d_in[2];
  const float* wk = (const float*)d_in[3];
  const float* bk = (const float*)d_in[4];
  const float* wv = (const float*)d_in[5];
  const float* bv = (const float*)d_in[6];
  const float* wo = (const float*)d_in[7];
  const float* bo = (const float*)d_in[8];
  const float* w1 = (const float*)d_in[9];
  const float* b1 = (const float*)d_in[10];
  const float* w2 = (const float*)d_in[11];
  const float* b2 = (const float*)d_in[12];
  const float* g1 = (const float*)d_in[13];
  const float* be1 = (const float*)d_in[14];
  const float* g2 = (const float*)d_in[15];
  const float* be2 = (const float*)d_in[16];
  float* out = (float*)d_out;

  // ws: bf16 weights (24 MB) + 6 x 8 MB bf16 slots
  u16* W = (u16*)d_ws;
  const size_t M1 = (size_t)1 << 20;
  u16* wqT = W;              // [1024,1024]; wkT follows contiguously -> fused QK BT [2048,1024]
  u16* wkT = wqT + M1;
  u16* wvT = wkT + M1;
  u16* woT = wvT + M1;
  u16* w1T = woT + M1;       // [4096,1024]
  u16* w2T = w1T + 4 * M1;   // [1024,4096]
  u16* arena = w2T + 4 * M1;
  const size_t S8M = (size_t)8 << 20;
  u16* xb = arena;             // slot 0: x bf16; later X1
  u16* QKb = arena + S8M;      // slots 1-2: fused [8192, 2048] (Q cols 0..1023, K cols 1024..)
  u16* Vtb = arena + 3 * S8M;  // slot 3: V^T [1024][8192] (row=h*64+d, col=b*2048+t)
  u16* Cb = arena + 4 * S8M;   // slot 4 (ctx)
  u16* AO = arena + 5 * S8M;   // slot 5 (attn_out)
  u16* X1 = xb;                // ln1 out (xb dead after QK/Vt gemms)
  u16* F1 = QKb;               // ffn1 hidden = slots 1-4 (64 MB; QKb/Vtb/Cb dead)
  const int NOSPLIT = 1 << 30;

  dim3 blk(256);
  transpose4_k<<<dim3(16, 16, 4), blk, 0, stream>>>(wq, wk, wv, wo, wqT, wkT, wvT, woT);
  transpose_k<<<dim3(64, 16), blk, 0, stream>>>(w1, w1T, 1024, 4096);
  transpose_k<<<dim3(16, 64), blk, 0, stream>>>(w2, w2T, 4096, 1024);
  convert_k<<<4096, blk, 0, stream>>>(x, xb);

  // fused Q+K projection: C[8192,2048] = xb * [wqT;wkT]^T, bias split bq|bk
  gemm_bt<false, false><<<dim3(64, 16), blk, 0, stream>>>(xb, wqT, bq, bk, 1024, QKb, 8192,
                                                          2048, 1024, 0);
  // V computed transposed: Vt[d][t] = sum_k wvT[d][k]*x[t][k] + bv[d]
  gemm_bt<false, true><<<dim3(8, 64), blk, 0, stream>>>(wvT, xb, bv, bv, NOSPLIT, Vtb, 1024,
                                                        8192, 1024, 0);

  // attention (Q/K strided 2048 in the fused buffer; K base pre-offset)
  attn_k<<<dim3(16, 16, 4), blk, 0, stream>>>(QKb, QKb + 1024, Vtb, Cb);

  // output projection + LN1
  gemm_bt<false, false><<<dim3(64, 8), blk, 0, stream>>>(Cb, woT, bo, bo, NOSPLIT, AO, 8192,
                                                         1024, 1024, 0);
  ln_k<true, false, false><<<2048, blk, 0, stream>>>(x, AO, g1, be1, X1);

  // FFN
  gemm_bt<false, false><<<dim3(64, 32), blk, 0, stream>>>(X1, w1T, b1, b1, NOSPLIT, F1, 8192,
                                                          4096, 1024, 1);
  gemm_bt<true, false><<<dim3(64, 8), blk, 0, stream>>>(F1, w2T, b2, b2, NOSPLIT, out, 8192,
                                                        1024, 4096, 0);
  ln_k<false, true, true><<<2048, blk, 0, stream>>>(X1, out, g2, be2, out);
}